// Round 1
// baseline (284.887 us; speedup 1.0000x reference)
//
#include <hip/hip_runtime.h>

#define TN 64
#define NB 2
#define CH 8
#define HH 128
#define WW 128
#define HW (HH*WW)        // 16384
#define CHW (CH*HW)       // 131072
#define NCHW (NB*CHW)     // 262144

// ---------------------------------------------------------------------------
// K1: psp1 alpha filter (tau=1). One thread per (n,c,h,w) element.
// Reads input [N,C,H,W,T] (t-contiguous per thread, float4), writes
// psp1 in t-major planes [T][N][C][H][W] (coalesced across lanes).
// ---------------------------------------------------------------------------
__global__ __launch_bounds__(256) void k_psp1(const float* __restrict__ x,
                                              float* __restrict__ psp1) {
    int e = blockIdx.x * blockDim.x + threadIdx.x;
    if (e >= NCHW) return;
    const float d1 = 0.36787944117144233f;  // exp(-1)
    const float c1 = 2.7182818284590452f;   // e * Ts/tau * Ts
    float P = 0.f, Q = 0.f;
    const float4* xe = reinterpret_cast<const float4*>(x + (size_t)e * TN);
    #pragma unroll
    for (int t4 = 0; t4 < TN / 4; ++t4) {
        float4 xv = xe[t4];
        float xs[4] = {xv.x, xv.y, xv.z, xv.w};
        #pragma unroll
        for (int j = 0; j < 4; ++j) {
            Q = d1 * (Q + P);
            P = d1 * P + xs[j];
            psp1[(size_t)(t4 * 4 + j) * NCHW + e] = c1 * Q;
        }
    }
}

// ---------------------------------------------------------------------------
// K2: conv1 5x5 pad=2, 8->8 channels, batched over T*N images.
// Block = 256 threads = 16x16 spatial tile; 8 output-channel accs per thread.
// ---------------------------------------------------------------------------
__global__ __launch_bounds__(256) void k_conv1(const float* __restrict__ in,
                                               const float* __restrict__ w1,
                                               float* __restrict__ outp) {
    __shared__ float tile[CH][20][20];
    const int img = blockIdx.y;              // t*NB + n, 0..127
    const int tid = blockIdx.x;              // 0..63
    const int h0 = (tid >> 3) * 16, w0 = (tid & 7) * 16;
    const int ty = threadIdx.x >> 4, tx = threadIdx.x & 15;
    const float* base = in + (size_t)img * CHW;

    for (int idx = threadIdx.x; idx < CH * 400; idx += 256) {
        int c = idx / 400;
        int r = idx % 400;
        int lh = r / 20, lw = r % 20;
        int gh = h0 + lh - 2, gw = w0 + lw - 2;
        float v = 0.f;
        if (gh >= 0 && gh < HH && gw >= 0 && gw < WW)
            v = base[c * HW + gh * WW + gw];
        tile[c][lh][lw] = v;
    }
    __syncthreads();

    float acc[CH];
    #pragma unroll
    for (int co = 0; co < CH; ++co) acc[co] = 0.f;

    #pragma unroll
    for (int ci = 0; ci < CH; ++ci) {
        float win[25];
        #pragma unroll
        for (int dy = 0; dy < 5; ++dy)
            #pragma unroll
            for (int dx = 0; dx < 5; ++dx)
                win[dy * 5 + dx] = tile[ci][ty + dy][tx + dx];
        #pragma unroll
        for (int co = 0; co < CH; ++co) {
            float a = acc[co];
            #pragma unroll
            for (int k = 0; k < 25; ++k)
                a = fmaf(w1[(co * CH + ci) * 25 + k], win[k], a);
            acc[co] = a;
        }
    }

    float* ob = outp + (size_t)img * CHW + (h0 + ty) * WW + (w0 + tx);
    #pragma unroll
    for (int co = 0; co < CH; ++co) ob[co * HW] = acc[co];
}

// ---------------------------------------------------------------------------
// K3: LIF1 (theta=30, tauRef=1) + psp2 alpha filter (tau=2), fused pointwise.
// ---------------------------------------------------------------------------
__global__ __launch_bounds__(256) void k_lif1_psp2(const float* __restrict__ u1,
                                                   float* __restrict__ psp2) {
    int e = blockIdx.x * blockDim.x + threadIdx.x;
    if (e >= NCHW) return;
    const float dr = 0.36787944117144233f;  // exp(-1)
    const float rg = 81.54845485377136f;    // 30*e
    const float th = 30.f;
    const float d2 = 0.60653065971263342f;  // exp(-0.5)
    const float c2 = 1.35914091422952262f;  // e/2
    float Pr = 0.f, Qr = 0.f, P2 = 0.f, Q2 = 0.f;
    #pragma unroll 8
    for (int t = 0; t < TN; ++t) {
        Qr = dr * (Qr + Pr);
        float u = u1[(size_t)t * NCHW + e];
        float s = (u - rg * Qr >= th) ? 1.0f : 0.0f;
        Pr = dr * Pr + s;
        Q2 = d2 * (Q2 + P2);
        P2 = d2 * P2 + s;
        psp2[(size_t)t * NCHW + e] = c2 * Q2;
    }
}

// ---------------------------------------------------------------------------
// K4: conv2 3x3 pad=1, 8->8 channels, batched over T*N images.
// ---------------------------------------------------------------------------
__global__ __launch_bounds__(256) void k_conv2(const float* __restrict__ in,
                                               const float* __restrict__ w2,
                                               float* __restrict__ outp) {
    __shared__ float tile[CH][18][18];
    const int img = blockIdx.y;
    const int tid = blockIdx.x;
    const int h0 = (tid >> 3) * 16, w0 = (tid & 7) * 16;
    const int ty = threadIdx.x >> 4, tx = threadIdx.x & 15;
    const float* base = in + (size_t)img * CHW;

    for (int idx = threadIdx.x; idx < CH * 324; idx += 256) {
        int c = idx / 324;
        int r = idx % 324;
        int lh = r / 18, lw = r % 18;
        int gh = h0 + lh - 1, gw = w0 + lw - 1;
        float v = 0.f;
        if (gh >= 0 && gh < HH && gw >= 0 && gw < WW)
            v = base[c * HW + gh * WW + gw];
        tile[c][lh][lw] = v;
    }
    __syncthreads();

    float acc[CH];
    #pragma unroll
    for (int co = 0; co < CH; ++co) acc[co] = 0.f;

    #pragma unroll
    for (int ci = 0; ci < CH; ++ci) {
        float win[9];
        #pragma unroll
        for (int dy = 0; dy < 3; ++dy)
            #pragma unroll
            for (int dx = 0; dx < 3; ++dx)
                win[dy * 3 + dx] = tile[ci][ty + dy][tx + dx];
        #pragma unroll
        for (int co = 0; co < CH; ++co) {
            float a = acc[co];
            #pragma unroll
            for (int k = 0; k < 9; ++k)
                a = fmaf(w2[(co * CH + ci) * 9 + k], win[k], a);
            acc[co] = a;
        }
    }

    float* ob = outp + (size_t)img * CHW + (h0 + ty) * WW + (w0 + tx);
    #pragma unroll
    for (int co = 0; co < CH; ++co) ob[co * HW] = acc[co];
}

// ---------------------------------------------------------------------------
// K5: LIF2 (theta=50, tauRef=2). Buffers 64 spikes in registers, writes
// output [N,C,H,W,T] (t-contiguous per thread) as float4.
// ---------------------------------------------------------------------------
__global__ __launch_bounds__(256) void k_lif2(const float* __restrict__ u2,
                                              float* __restrict__ outp) {
    int e = blockIdx.x * blockDim.x + threadIdx.x;
    if (e >= NCHW) return;
    const float dr = 0.60653065971263342f;  // exp(-0.5)
    const float rg = 67.95704571147613f;    // 25*e
    const float th = 50.f;
    float Pr = 0.f, Qr = 0.f;
    float sv[TN];
    #pragma unroll
    for (int t = 0; t < TN; ++t) {
        Qr = dr * (Qr + Pr);
        float u = u2[(size_t)t * NCHW + e];
        float s = (u - rg * Qr >= th) ? 1.0f : 0.0f;
        Pr = dr * Pr + s;
        sv[t] = s;
    }
    float4* o = reinterpret_cast<float4*>(outp + (size_t)e * TN);
    #pragma unroll
    for (int i = 0; i < TN / 4; ++i)
        o[i] = make_float4(sv[4 * i], sv[4 * i + 1], sv[4 * i + 2], sv[4 * i + 3]);
}

// ---------------------------------------------------------------------------
extern "C" void kernel_launch(void* const* d_in, const int* in_sizes, int n_in,
                              void* d_out, int out_size, void* d_ws, size_t ws_size,
                              hipStream_t stream) {
    const float* x  = (const float*)d_in[0];   // [2,8,128,128,64]
    const float* w1 = (const float*)d_in[1];   // [8,8,5,5]
    const float* w2 = (const float*)d_in[2];   // [8,8,3,3]
    float* out = (float*)d_out;                // [2,8,128,128,64]

    // ping-pong buffers: 2 x 16,777,216 floats = 128 MB total
    float* bufA = (float*)d_ws;                       // psp1, then psp2
    float* bufB = bufA + (size_t)TN * NCHW;           // u1,   then u2

    dim3 blk(256);
    dim3 grd_pt(NCHW / 256);          // 1024 blocks, pointwise kernels
    dim3 grd_cv(64, TN * NB);         // 64 tiles x 128 images

    k_psp1<<<grd_pt, blk, 0, stream>>>(x, bufA);
    k_conv1<<<grd_cv, blk, 0, stream>>>(bufA, w1, bufB);
    k_lif1_psp2<<<grd_pt, blk, 0, stream>>>(bufB, bufA);
    k_conv2<<<grd_cv, blk, 0, stream>>>(bufA, w2, bufB);
    k_lif2<<<grd_pt, blk, 0, stream>>>(bufB, out);
}